// Round 2
// baseline (788.888 us; speedup 1.0000x reference)
//
#include <hip/hip_runtime.h>

// Problem constants
constexpr int Bb = 8, Ll = 2048, Ww = 1024;
constexpr int BL = Bb * Ll;              // 16384

typedef short bf16x8 __attribute__((ext_vector_type(8)));
typedef float f32x4  __attribute__((ext_vector_type(4)));

// ---------- bf16 helpers (RNE) ----------
__device__ inline unsigned short f2bf(float f) {
    union { float f; unsigned u; } v; v.f = f;
    unsigned u = v.u;
    unsigned r = (u + 0x7fffu + ((u >> 16) & 1u)) >> 16;
    return (unsigned short)r;
}
__device__ inline float bf2f(unsigned short h) {
    union { unsigned u; float f; } v; v.u = ((unsigned)h) << 16;
    return v.f;
}

// ---------- async global->LDS, 16B per lane ----------
__device__ inline void gl_lds16(const unsigned short* g, unsigned short* l) {
    __builtin_amdgcn_global_load_lds(
        (const __attribute__((address_space(1))) unsigned int*)g,
        (__attribute__((address_space(3))) unsigned int*)l, 16, 0, 0);
}

// ---------- kernel 0: mask dtype detect + expand to float (1=valid, 0=padded) ----------
__global__ void mask_expand_kernel(const void* __restrict__ mraw, float* __restrict__ maskf) {
    const unsigned char* mb = (const unsigned char*)mraw;
    const unsigned* mw = (const unsigned*)mraw;
    __shared__ int s_nonint, s_notf, s_hasf;
    if (threadIdx.x == 0) { s_nonint = 0; s_notf = 0; s_hasf = 0; }
    __syncthreads();
    int nonint = 0, notf = 0, hasf = 0;
    for (int i = threadIdx.x; i < BL; i += blockDim.x) {
        unsigned char c = mb[i];
        if ((i & 3) && c) nonint = 1;
    }
    for (int i = threadIdx.x; i < BL / 4; i += blockDim.x) {
        unsigned w = mw[i];
        if (w == 0x3f800000u) hasf = 1; else if (w) notf = 1;
    }
    if (nonint) atomicOr(&s_nonint, 1);
    if (notf)   atomicOr(&s_notf, 1);
    if (hasf)   atomicOr(&s_hasf, 1);
    __syncthreads();
    int is_f32  = (!s_notf) && s_hasf;
    int is_bool = (!is_f32) && s_nonint;
    for (int i = threadIdx.x; i < BL; i += blockDim.x) {
        int masked;
        if (is_bool) masked = (mb[i] != 0);
        else         masked = (mw[i] != 0u);
        maskf[i] = masked ? 0.0f : 1.0f;
    }
}

// ---------- kernel 1a: conv_w fp32 [g][o][c][k] -> pre-tiled swizzled bf16 images ----------
// Image per (g, nt, cs): 128 rows (n' = nt*128+r, n' = k*512+o) x 32 channels, stored as
// 16B chunks at addr16(r,q) = r*4 + (q ^ (r&3)).  20 ntiles/group (k = nt>>2, o0=(nt&3)*128).
__global__ void wconv_kernel(const float* __restrict__ conv_w, unsigned short* __restrict__ w_t) {
    int gnt = blockIdx.x >> 2;           // 0..39 = g*20+nt
    int part = blockIdx.x & 3;
    int g = gnt / 20, nt = gnt % 20;
    int k = nt >> 2, o0 = (nt & 3) * 128;
    int tid = threadIdx.x;
    #pragma unroll
    for (int it = 0; it < 8; it++) {
        int chunk = part * 2048 + it * 256 + tid;    // 0..8191 per (g,nt)
        int r = chunk >> 6;                           // tile row
        int cq = chunk & 63;
        int cs = cq >> 2, q = cq & 3;
        int o = o0 + r;
        int c0 = cs * 32 + q * 8;                     // channel within group
        const float* src = conv_w + (((size_t)(g * 512 + o) * 512 + c0) * 5 + k);
        ushort4 lo, hi;
        lo.x = f2bf(src[0]);  lo.y = f2bf(src[5]);  lo.z = f2bf(src[10]); lo.w = f2bf(src[15]);
        hi.x = f2bf(src[20]); hi.y = f2bf(src[25]); hi.z = f2bf(src[30]); hi.w = f2bf(src[35]);
        int dst16 = (gnt * 16 + cs) * 512 + r * 4 + (q ^ (r & 3));
        *(ushort4*)&w_t[(size_t)dst16 * 8]     = lo;
        *(ushort4*)&w_t[(size_t)dst16 * 8 + 4] = hi;
    }
}

// ---------- kernel 1b: offsets (tanh(x@w_off)+pos -> idx/weights) + x -> tiled bf16 ----------
// x_t image per (b, lt, cs): 128 l-rows x 32 channels, same swizzled chunk layout.
__global__ __launch_bounds__(256) void offsets_kernel(
    const float* __restrict__ x, const float* __restrict__ w_off, const float* __restrict__ b_off,
    unsigned short* __restrict__ x_t, int* __restrict__ idx0, int* __restrict__ idx1,
    float* __restrict__ w0a, float* __restrict__ w1a)
{
    int bl = blockIdx.x;
    int b = bl >> 11;
    int l = bl & (Ll - 1);
    int lt = l >> 7, r = l & 127;
    int tid = threadIdx.x;
    const float* xr = x + (size_t)bl * Ww;
    float4 v = *(const float4*)(xr + tid * 4);
    ushort4 xb4 = { f2bf(v.x), f2bf(v.y), f2bf(v.z), f2bf(v.w) };
    int cs = tid >> 3, q = (tid >> 1) & 3, half = tid & 1;
    int dst16 = ((b * 16 + lt) * 32 + cs) * 512 + r * 4 + (q ^ (r & 3));
    *(ushort4*)&x_t[(size_t)dst16 * 8 + half * 4] = xb4;

    float acc[5] = {0.f, 0.f, 0.f, 0.f, 0.f};
    int c = tid * 4;
    const float* vv = (const float*)&v;
    #pragma unroll
    for (int j = 0; j < 4; j++) {
        float xv = vv[j];
        #pragma unroll
        for (int k = 0; k < 5; k++) acc[k] += xv * w_off[(c + j) * 5 + k];
    }
    #pragma unroll
    for (int k = 0; k < 5; k++)
        for (int off = 32; off; off >>= 1) acc[k] += __shfl_down(acc[k], off);

    __shared__ float red[4][5];
    int wave = tid >> 6, lane = tid & 63;
    if (lane == 0) {
        #pragma unroll
        for (int k = 0; k < 5; k++) red[wave][k] = acc[k];
    }
    __syncthreads();
    if (tid < 5) {
        int k = tid;
        float s = red[0][k] + red[1][k] + red[2][k] + red[3][k] + b_off[k];
        float offv = tanhf(s) * 2.0f;
        float pos = (float)l + (float)(k - 2) + offv;
        float p0 = floorf(pos);
        float frac = pos - p0;
        int i0 = (int)p0;
        int i1 = i0 + 1;
        int v0 = (i0 >= 0) && (i0 < Ll);
        int v1 = (i1 >= 0) && (i1 < Ll);
        idx0[bl * 5 + k] = min(max(i0, 0), Ll - 1);
        idx1[bl * 5 + k] = min(max(i1, 0), Ll - 1);
        w0a[bl * 5 + k] = v0 ? (1.0f - frac) : 0.0f;
        w1a[bl * 5 + k] = v1 ? frac : 0.0f;
    }
}

// ---------- kernel 2: pure GEMM per batch: Z[k][l][w] = x_b @ W' (per group) ----------
// 128x128 tile, BK=64, 4 waves (2x2 of 64x64), global_load_lds staging of pre-tiled images.
__global__ __launch_bounds__(256) void gemm_kernel(
    const unsigned short* __restrict__ x_t, const unsigned short* __restrict__ w_t,
    unsigned short* __restrict__ Z, int b)
{
    __shared__ unsigned short As[8192];   // 2 images of 128x32 (16 KB)
    __shared__ unsigned short Bs[8192];
    const int tid = threadIdx.x;
    const int gx = blockIdx.x;            // g*20+nt
    const int mt = blockIdx.y;            // 0..15
    const int g = gx / 20, nt = gx % 20;
    const int lane = tid & 63, wave = tid >> 6;
    const int wr = (wave >> 1) * 64, wc = (wave & 1) * 64;
    const int l15 = lane & 15, l4 = lane >> 4;
    const int sw = (l4 ^ (l15 & 3)) * 8;  // swizzled chunk offset, in ushorts

    const unsigned short* Ab = x_t + ((size_t)((b * 16 + mt) * 32 + g * 16)) * 4096 + tid * 8;
    const unsigned short* Bp = w_t + ((size_t)gx * 16) * 4096 + tid * 8;

    f32x4 acc[4][4] = {};
    for (int ks = 0; ks < 8; ks++) {
        const unsigned short* ga = Ab + ks * 8192;
        const unsigned short* gb = Bp + ks * 8192;
        #pragma unroll
        for (int c = 0; c < 4; c++) {
            gl_lds16(ga + c * 2048, &As[tid * 8 + c * 2048]);
            gl_lds16(gb + c * 2048, &Bs[tid * 8 + c * 2048]);
        }
        __syncthreads();                   // drains vmcnt (DMA) for this tile
        bf16x8 af[2][4], bfr[2][4];
        #pragma unroll
        for (int kk = 0; kk < 2; kk++)
            #pragma unroll
            for (int i = 0; i < 4; i++) {
                af[kk][i]  = *(const bf16x8*)&As[kk * 4096 + (wr + i * 16 + l15) * 32 + sw];
                bfr[kk][i] = *(const bf16x8*)&Bs[kk * 4096 + (wc + i * 16 + l15) * 32 + sw];
            }
        #pragma unroll
        for (int kk = 0; kk < 2; kk++)
            #pragma unroll
            for (int i = 0; i < 4; i++)
                #pragma unroll
                for (int j = 0; j < 4; j++)
                    acc[i][j] = __builtin_amdgcn_mfma_f32_16x16x32_bf16(af[kk][i], bfr[kk][j], acc[i][j], 0, 0, 0);
        __syncthreads();                   // ds_reads done before next DMA overwrites
    }
    // epilogue: write Z[k][l][w] bf16 (no bias here; bias added in gather pass)
    const int k = nt >> 2, o0 = (nt & 3) * 128;
    unsigned short* Zp = Z + ((size_t)k * Ll) * Ww + (g * 512 + o0);
    #pragma unroll
    for (int j = 0; j < 4; j++) {
        int col = wc + j * 16 + l15;
        #pragma unroll
        for (int i = 0; i < 4; i++) {
            int row0 = mt * 128 + wr + i * 16 + l4 * 4;
            #pragma unroll
            for (int rr = 0; rr < 4; rr++)
                Zp[(size_t)(row0 + rr) * Ww + col] = f2bf(acc[i][j][rr]);
        }
    }
}

// ---------- kernel 3: gather/lerp + bias + LayerNorm + mask + pooled partials (per batch) ----------
__global__ __launch_bounds__(256) void gather_kernel(
    const unsigned short* __restrict__ Z, const int* __restrict__ idx0, const int* __restrict__ idx1,
    const float* __restrict__ w0a, const float* __restrict__ w1a, const float* __restrict__ conv_b,
    const float* __restrict__ gamma, const float* __restrict__ beta, const float* __restrict__ maskf,
    float* __restrict__ pooled, int b)
{
    int tid = threadIdx.x;
    int c = tid * 4;
    int wave = tid >> 6, lane = tid & 63;
    __shared__ float red[2][4];
    float cb[4], g4[4], be4[4], pacc[4] = {0.f, 0.f, 0.f, 0.f};
    #pragma unroll
    for (int j = 0; j < 4; j++) { cb[j] = conv_b[c + j]; g4[j] = gamma[c + j]; be4[j] = beta[c + j]; }

    for (int rr = 0; rr < 4; rr++) {
        int l = blockIdx.x * 4 + rr;
        int bl = b * Ll + l;
        if (maskf[bl] == 0.0f) continue;           // uniform across block
        float h4[4] = {cb[0], cb[1], cb[2], cb[3]};
        #pragma unroll
        for (int k = 0; k < 5; k++) {
            int i0 = idx0[bl * 5 + k], i1 = idx1[bl * 5 + k];
            float w0 = w0a[bl * 5 + k], w1 = w1a[bl * 5 + k];
            ushort4 z0 = *(const ushort4*)(Z + ((size_t)k * Ll + i0) * Ww + c);
            ushort4 z1 = *(const ushort4*)(Z + ((size_t)k * Ll + i1) * Ww + c);
            h4[0] += w0 * bf2f(z0.x) + w1 * bf2f(z1.x);
            h4[1] += w0 * bf2f(z0.y) + w1 * bf2f(z1.y);
            h4[2] += w0 * bf2f(z0.z) + w1 * bf2f(z1.z);
            h4[3] += w0 * bf2f(z0.w) + w1 * bf2f(z1.w);
        }
        float s1 = h4[0] + h4[1] + h4[2] + h4[3];
        float s2 = h4[0]*h4[0] + h4[1]*h4[1] + h4[2]*h4[2] + h4[3]*h4[3];
        for (int off = 32; off; off >>= 1) {
            s1 += __shfl_down(s1, off);
            s2 += __shfl_down(s2, off);
        }
        __syncthreads();
        if (lane == 0) { red[0][wave] = s1; red[1][wave] = s2; }
        __syncthreads();
        float S1 = red[0][0] + red[0][1] + red[0][2] + red[0][3];
        float S2 = red[1][0] + red[1][1] + red[1][2] + red[1][3];
        float mu = S1 * (1.0f / 1024.0f);
        float var = S2 * (1.0f / 1024.0f) - mu * mu;
        float rstd = rsqrtf(var + 1e-5f);
        #pragma unroll
        for (int j = 0; j < 4; j++) pacc[j] += (h4[j] - mu) * rstd * g4[j] + be4[j];
    }
    #pragma unroll
    for (int j = 0; j < 4; j++) atomicAdd(&pooled[b * Ww + c + j], pacc[j]);
}

// ---------- kernel 4: lengths + projection ----------
__global__ void final_kernel(const float* __restrict__ pooled, const float* __restrict__ maskf,
                             const float* __restrict__ proj_w, const float* __restrict__ proj_b,
                             float* __restrict__ out)
{
    int b = blockIdx.x;
    int tid = threadIdx.x;
    float len = 0.f, dot = 0.f;
    for (int l = tid; l < Ll; l += 256) len += maskf[b * Ll + l];
    for (int c = tid; c < Ww; c += 256) dot += pooled[b * Ww + c] * proj_w[c];
    for (int off = 32; off; off >>= 1) {
        len += __shfl_down(len, off);
        dot += __shfl_down(dot, off);
    }
    __shared__ float rl[4], rd[4];
    int wave = tid >> 6, lane = tid & 63;
    if (lane == 0) { rl[wave] = len; rd[wave] = dot; }
    __syncthreads();
    if (tid == 0) {
        float Lt = rl[0] + rl[1] + rl[2] + rl[3];
        float Dt = rd[0] + rd[1] + rd[2] + rd[3];
        out[b] = Dt / fmaxf(Lt, 1.0f) + proj_b[0];
    }
}

// ---------- workspace layout (bytes, 16B-aligned) ----------
// maskf  @        0  (65536)
// pooled @    65536  (32768)
// idx0   @    98304  (327680)
// idx1   @   425984  (327680)
// w0a    @   753664  (327680)
// w1a    @  1081344  (327680)
// w_t    @  1409024  (5242880)    640 images x 8KB
// x_t    @  6651904  (33554432)   4096 images x 8KB
// Z      @ 40206336  (20971520)   [5][2048][1024] bf16, reused per batch
// total 61,177,856 B

extern "C" void kernel_launch(void* const* d_in, const int* in_sizes, int n_in,
                              void* d_out, int out_size, void* d_ws, size_t ws_size,
                              hipStream_t stream)
{
    const float* x      = (const float*)d_in[0];
    const void*  mask   = d_in[1];
    const float* w_off  = (const float*)d_in[2];
    const float* b_off  = (const float*)d_in[3];
    const float* conv_w = (const float*)d_in[4];
    const float* conv_b = (const float*)d_in[5];
    const float* gamma  = (const float*)d_in[6];
    const float* beta   = (const float*)d_in[7];
    const float* proj_w = (const float*)d_in[8];
    const float* proj_b = (const float*)d_in[9];
    float* out = (float*)d_out;

    char* ws = (char*)d_ws;
    float* maskf         = (float*)(ws + 0);
    float* pooled        = (float*)(ws + 65536);
    int*   idx0          = (int*)(ws + 98304);
    int*   idx1          = (int*)(ws + 425984);
    float* w0a           = (float*)(ws + 753664);
    float* w1a           = (float*)(ws + 1081344);
    unsigned short* w_t  = (unsigned short*)(ws + 1409024);
    unsigned short* x_t  = (unsigned short*)(ws + 6651904);
    unsigned short* Z    = (unsigned short*)(ws + 40206336);

    hipMemsetAsync(pooled, 0, Bb * Ww * sizeof(float), stream);
    mask_expand_kernel<<<1, 256, 0, stream>>>(mask, maskf);
    wconv_kernel<<<160, 256, 0, stream>>>(conv_w, w_t);
    offsets_kernel<<<BL, 256, 0, stream>>>(x, w_off, b_off, x_t, idx0, idx1, w0a, w1a);
    for (int b = 0; b < Bb; b++) {
        gemm_kernel<<<dim3(40, 16), 256, 0, stream>>>(x_t, w_t, Z, b);
        gather_kernel<<<512, 256, 0, stream>>>(Z, idx0, idx1, w0a, w1a, conv_b,
                                               gamma, beta, maskf, pooled, b);
    }
    final_kernel<<<8, 256, 0, stream>>>(pooled, maskf, proj_w, proj_b, out);
}